// Round 4
// baseline (360.059 us; speedup 1.0000x reference)
//
#include <hip/hip_runtime.h>

#define NBATCH 16
#define NPTS   2048
#define MQ     2025
#define CWDIM  512
#define NROWS  32400

typedef __attribute__((ext_vector_type(8))) short bf16x8;
typedef __attribute__((ext_vector_type(4))) float f32x4;
typedef unsigned int as1_u32 __attribute__((address_space(1)));
typedef unsigned int as3_u32 __attribute__((address_space(3)));

// ---------- helpers ----------
__device__ __forceinline__ unsigned fkey(float f) {
  unsigned u = __float_as_uint(f);
  return (u & 0x80000000u) ? ~u : (u | 0x80000000u);
}
__device__ __forceinline__ float funkey(unsigned u) {
  unsigned v = (u & 0x80000000u) ? (u ^ 0x80000000u) : ~u;
  return __uint_as_float(v);
}
__device__ __forceinline__ unsigned short f2bf(float f) {  // RNE f32->bf16
  unsigned u = __float_as_uint(f);
  u = (u + 0x7FFFu + ((u >> 16) & 1u)) >> 16;
  return (unsigned short)u;
}
__device__ __forceinline__ void gload_lds16(const void* g, void* l) {
  __builtin_amdgcn_global_load_lds((const as1_u32*)g, (as3_u32*)l, 16, 0, 0);
}

// =====================================================================
// Generic 32x32 transpose + f32->bf16 convert.
// =====================================================================
__global__ __launch_bounds__(256) void tconv_kernel(
    const float* __restrict__ f1w2, const float* __restrict__ f2w2,
    const float* __restrict__ ew2,  const float* __restrict__ ew3,
    unsigned short* __restrict__ w2T, unsigned short* __restrict__ ew2T,
    unsigned short* __restrict__ ew3T)
{
  __shared__ float tile[32][33];
  const int blk = blockIdx.x;
  const float* src; unsigned short* dst; int K, N, tidx;
  if (blk < 256)      { src = f1w2; dst = w2T;            K = 512; N = 512; tidx = blk; }
  else if (blk < 512) { src = f2w2; dst = w2T + 262144;   K = 512; N = 512; tidx = blk - 256; }
  else if (blk < 520) { src = ew2;  dst = ew2T;           K = 64;  N = 128; tidx = blk - 512; }
  else                { src = ew3;  dst = ew3T;           K = 128; N = 512; tidx = blk - 520; }
  const int ntn = N >> 5;
  const int kt = tidx / ntn, nt = tidx - kt * ntn;
  const int tx = threadIdx.x & 31, ty = threadIdx.x >> 5;
  #pragma unroll
  for (int j = 0; j < 4; ++j)
    tile[ty + 8 * j][tx] = src[(size_t)(kt * 32 + ty + 8 * j) * N + nt * 32 + tx];
  __syncthreads();
  #pragma unroll
  for (int j = 0; j < 4; ++j)
    dst[(size_t)(nt * 32 + ty + 8 * j) * K + kt * 32 + tx] = f2bf(tile[tx][ty + 8 * j]);
}

// =====================================================================
// Encoder (MFMA): block = 64 points, 512 thr = 8 waves.  (unchanged, passed)
// =====================================================================
__global__ __launch_bounds__(512, 4) void enc2_kernel(
    const float* __restrict__ pts,
    const float* __restrict__ ew1, const float* __restrict__ eb1,
    const unsigned short* __restrict__ ew2T, const float* __restrict__ eb2,
    const unsigned short* __restrict__ ew3T, const float* __restrict__ eb3,
    unsigned* __restrict__ keys)
{
  __shared__ unsigned short h1s[64 * 64];
  __shared__ unsigned short h2s[64 * 128];
  __shared__ float s_pts[64][4];
  const int t = threadIdx.x;
  const int b = blockIdx.x >> 5, p0 = (blockIdx.x & 31) << 6;
  if (t < 64)
    *(float4*)&s_pts[t][0] = *(const float4*)(pts + ((size_t)b * NPTS + p0 + t) * 4);
  __syncthreads();

  {
    const int c = t & 63;
    const float w0 = ew1[c], w1 = ew1[64 + c], w2 = ew1[128 + c], w3 = ew1[192 + c];
    const float bb = eb1[c];
    #pragma unroll
    for (int i = 0; i < 8; ++i) {
      const int p = i * 8 + (t >> 6);
      float acc = bb + s_pts[p][0] * w0 + s_pts[p][1] * w1 + s_pts[p][2] * w2 + s_pts[p][3] * w3;
      unsigned byte = ((unsigned)p << 7) + ((unsigned)c << 1);
      byte ^= ((unsigned)(p & 7)) << 4;
      h1s[byte >> 1] = f2bf(fmaxf(acc, 0.f));
    }
  }
  __syncthreads();

  const int wv = t >> 6, lane = t & 63, l15 = lane & 15, hi = lane >> 4;

  {
    f32x4 acc[4];
    #pragma unroll
    for (int m = 0; m < 4; ++m) acc[m] = (f32x4){0.f, 0.f, 0.f, 0.f};
    const int col = 16 * wv + l15;
    #pragma unroll
    for (int kk = 0; kk < 64; kk += 32) {
      bf16x8 bv = *(const bf16x8*)(ew2T + (size_t)col * 64 + kk + hi * 8);
      #pragma unroll
      for (int m = 0; m < 4; ++m) {
        const int row = 16 * m + l15;
        unsigned byte = ((unsigned)row << 7) + ((unsigned)((kk + hi * 8)) << 1);
        byte ^= ((unsigned)(row & 7)) << 4;
        bf16x8 av = *(const bf16x8*)&h1s[byte >> 1];
        acc[m] = __builtin_amdgcn_mfma_f32_16x16x32_bf16(av, bv, acc[m], 0, 0, 0);
      }
    }
    const float b2c = eb2[col];
    #pragma unroll
    for (int m = 0; m < 4; ++m)
      #pragma unroll
      for (int r = 0; r < 4; ++r) {
        const int row = 16 * m + hi * 4 + r;
        unsigned byte = ((unsigned)row << 8) + ((unsigned)col << 1);
        byte ^= ((unsigned)(row & 7)) << 4;
        h2s[byte >> 1] = f2bf(fmaxf(acc[m][r] + b2c, 0.f));
      }
  }
  __syncthreads();

  {
    f32x4 acc[4][4];
    #pragma unroll
    for (int m = 0; m < 4; ++m)
      #pragma unroll
      for (int n = 0; n < 4; ++n) acc[m][n] = (f32x4){0.f, 0.f, 0.f, 0.f};
    #pragma unroll
    for (int kk = 0; kk < 128; kk += 32) {
      bf16x8 av[4];
      #pragma unroll
      for (int m = 0; m < 4; ++m) {
        const int row = 16 * m + l15;
        unsigned byte = ((unsigned)row << 8) + ((unsigned)(kk + hi * 8) << 1);
        byte ^= ((unsigned)(row & 7)) << 4;
        av[m] = *(const bf16x8*)&h2s[byte >> 1];
      }
      #pragma unroll
      for (int n = 0; n < 4; ++n) {
        const int col = 64 * wv + 16 * n + l15;
        bf16x8 bv = *(const bf16x8*)(ew3T + (size_t)col * 128 + kk + hi * 8);
        #pragma unroll
        for (int m = 0; m < 4; ++m)
          acc[m][n] = __builtin_amdgcn_mfma_f32_16x16x32_bf16(av[m], bv, acc[m][n], 0, 0, 0);
      }
    }
    #pragma unroll
    for (int n = 0; n < 4; ++n) {
      const int col = 64 * wv + 16 * n + l15;
      float mx = -1e30f;
      #pragma unroll
      for (int m = 0; m < 4; ++m)
        #pragma unroll
        for (int r = 0; r < 4; ++r) mx = fmaxf(mx, acc[m][n][r]);
      mx = fmaxf(mx, __shfl_xor(mx, 16));
      mx = fmaxf(mx, __shfl_xor(mx, 32));
      if (hi == 0) atomicMax(&keys[b * CWDIM + col], fkey(mx + eb3[col]));
    }
  }
}

__global__ __launch_bounds__(256) void decode_kernel(const unsigned* __restrict__ keys,
                                                     float* __restrict__ theta) {
  int i = blockIdx.x * 256 + threadIdx.x;
  theta[i] = funkey(keys[i]);
}

// =====================================================================
// h1base split-K x2: atomicAdd partials (h1b pre-zeroed by memset)
// =====================================================================
__global__ __launch_bounds__(256) void h1base_kernel(
    const float* __restrict__ theta,
    const float* __restrict__ f1w1, const float* __restrict__ f1b1,
    const float* __restrict__ f2w1, const float* __restrict__ f2b1,
    float* __restrict__ h1b)
{
  int gid = blockIdx.x * 256 + threadIdx.x;   // 32768
  int half = gid >> 14;
  int rem = gid & 16383;
  int stage = rem >> 13, bb = (rem >> 9) & 15, c = rem & 511;
  const float* w = stage ? f2w1 : f1w1;
  float acc = 0.f;
  if (half == 0) acc = stage ? f2b1[c] : f1b1[c];
  const float* th = theta + bb * 512 + half * 256;
  const float* wp = w + (size_t)(half * 256) * 512 + c;
  #pragma unroll 8
  for (int k = 0; k < 256; ++k) acc += th[k] * wp[(size_t)k * 512];
  atomicAdd(&h1b[rem], acc);
}

// =====================================================================
// fold3: M=64-row blocks (padded to 32448 = 507*64), N=512 in two 256-col
// passes, BK=64. m97-style 2-barrier K-loop: A computed to LDS, B staged
// via global_load_lds(16B). 8 waves = 2M x 4N, wave tile 32x64 per pass.
// =====================================================================
struct Fold3Smem {
  unsigned short sB[2048 * 8];   // 32 KB  chunk(k8,col) at (k8*256+col)*16B
  unsigned short sA[512 * 8];    // 8 KB   chunk(k8,row) at (k8*64+row)*16B
  float h1bL[2][2][512];         // 8 KB   [stage][b0/b1][c]
  float w1eL[3][512];            // 6 KB
  float b2s[512];                // 2 KB
  float w3s[3][512];             // 6 KB
  float red[8][32][3];           // 3 KB
  float ext[64][5];              // 1.25 KB (pad 5 -> conflict-free)
  int   rowb[64];
};

template <int ST>
__device__ __forceinline__ void fold3_stage(Fold3Smem& S, int t, int r0,
    const unsigned short* __restrict__ wst,   // 512x512 bf16 [col][k]
    const float* __restrict__ w1, const float* __restrict__ b2,
    const float* __restrict__ w3, const float* __restrict__ b3,
    float* __restrict__ out_pc)
{
  constexpr int NE = ST ? 3 : 2;
  const int wv = t >> 6, lane = t & 63, l15 = lane & 15, hi = lane >> 4;
  const int wm = wv >> 2, wn = wv & 3;

  // stage-constant LDS loads (one element per thread)
  {
    const int c = t;   // 512 threads == 512 cols
    S.w1eL[0][c] = w1[(size_t)512 * 512 + c];
    S.w1eL[1][c] = w1[(size_t)513 * 512 + c];
    if (NE == 3) S.w1eL[2][c] = w1[(size_t)514 * 512 + c];
    S.b2s[c] = b2[c];
    S.w3s[0][c] = w3[c * 3 + 0];
    S.w3s[1][c] = w3[c * 3 + 1];
    S.w3s[2][c] = w3[c * 3 + 2];
  }
  __syncthreads();

  float p[2][4][3];
  #pragma unroll
  for (int m = 0; m < 2; ++m)
    #pragma unroll
    for (int r = 0; r < 4; ++r)
      #pragma unroll
      for (int jj = 0; jj < 3; ++jj) p[m][r][jj] = 0.f;

  const int k8a = t >> 6, arow = t & 63;       // A-compute assignment
  const int sl = S.rowb[arow];

  for (int pass = 0; pass < 2; ++pass) {
    f32x4 acc[2][4];
    #pragma unroll
    for (int m = 0; m < 2; ++m)
      #pragma unroll
      for (int n = 0; n < 4; ++n) acc[m][n] = (f32x4){0.f, 0.f, 0.f, 0.f};

    const unsigned short* wB = wst + (size_t)(pass * 256) * 512;

    for (int kt = 0; kt < 8; ++kt) {
      const int kk = kt * 64;
      // ---- A-compute: thread -> chunk (k8a, arow), 8 values c = kk+k8a*8+j
      {
        const int cb = kk + k8a * 8;
        const float e0 = S.ext[arow][0], e1 = S.ext[arow][1];
        const float4 hb0 = *(const float4*)&S.h1bL[ST][sl][cb];
        const float4 hb1 = *(const float4*)&S.h1bL[ST][sl][cb + 4];
        const float4 wa0 = *(const float4*)&S.w1eL[0][cb];
        const float4 wa1 = *(const float4*)&S.w1eL[0][cb + 4];
        const float4 wb0 = *(const float4*)&S.w1eL[1][cb];
        const float4 wb1 = *(const float4*)&S.w1eL[1][cb + 4];
        float v0 = hb0.x + e0 * wa0.x + e1 * wb0.x;
        float v1 = hb0.y + e0 * wa0.y + e1 * wb0.y;
        float v2 = hb0.z + e0 * wa0.z + e1 * wb0.z;
        float v3 = hb0.w + e0 * wa0.w + e1 * wb0.w;
        float v4 = hb1.x + e0 * wa1.x + e1 * wb1.x;
        float v5 = hb1.y + e0 * wa1.y + e1 * wb1.y;
        float v6 = hb1.z + e0 * wa1.z + e1 * wb1.z;
        float v7 = hb1.w + e0 * wa1.w + e1 * wb1.w;
        if (NE == 3) {
          const float e2 = S.ext[arow][2];
          const float4 wc0 = *(const float4*)&S.w1eL[2][cb];
          const float4 wc1 = *(const float4*)&S.w1eL[2][cb + 4];
          v0 += e2 * wc0.x; v1 += e2 * wc0.y; v2 += e2 * wc0.z; v3 += e2 * wc0.w;
          v4 += e2 * wc1.x; v5 += e2 * wc1.y; v6 += e2 * wc1.z; v7 += e2 * wc1.w;
        }
        int4 pk;
        pk.x = (unsigned)f2bf(fmaxf(v0, 0.f)) | ((unsigned)f2bf(fmaxf(v1, 0.f)) << 16);
        pk.y = (unsigned)f2bf(fmaxf(v2, 0.f)) | ((unsigned)f2bf(fmaxf(v3, 0.f)) << 16);
        pk.z = (unsigned)f2bf(fmaxf(v4, 0.f)) | ((unsigned)f2bf(fmaxf(v5, 0.f)) << 16);
        pk.w = (unsigned)f2bf(fmaxf(v6, 0.f)) | ((unsigned)f2bf(fmaxf(v7, 0.f)) << 16);
        *(int4*)&S.sA[(size_t)t * 8] = pk;
      }
      // ---- B-stage: 4 wave-issues of 1 KB (global_load_lds width 16)
      #pragma unroll
      for (int i = 0; i < 4; ++i) {
        const int cidx = i * 8 + wv;                 // 0..31
        const int k8 = cidx >> 2, colb = (cidx & 3) * 64;
        const unsigned short* g = wB + (size_t)(colb + lane) * 512 + kk + k8 * 8;
        gload_lds16(g, &S.sB[(size_t)cidx * 512]);   // 512 ushorts = 1 KB
      }
      __syncthreads();
      // ---- MFMA: 16 per wave
      #pragma unroll
      for (int ks = 0; ks < 2; ++ks) {
        const int k8 = ks * 4 + hi;
        const bf16x8 a0 = *(const bf16x8*)&S.sA[(size_t)(k8 * 64 + wm * 32 + l15) * 8];
        const bf16x8 a1 = *(const bf16x8*)&S.sA[(size_t)(k8 * 64 + wm * 32 + 16 + l15) * 8];
        #pragma unroll
        for (int n = 0; n < 4; ++n) {
          const bf16x8 bv = *(const bf16x8*)&S.sB[(size_t)(k8 * 256 + wn * 64 + 16 * n + l15) * 8];
          acc[0][n] = __builtin_amdgcn_mfma_f32_16x16x32_bf16(a0, bv, acc[0][n], 0, 0, 0);
          acc[1][n] = __builtin_amdgcn_mfma_f32_16x16x32_bf16(a1, bv, acc[1][n], 0, 0, 0);
        }
      }
      __syncthreads();
    }

    // ---- layer-3 partials from acc (stays in registers across passes)
    #pragma unroll
    for (int n = 0; n < 4; ++n) {
      const int colG = pass * 256 + wn * 64 + 16 * n + l15;
      const float b2c = S.b2s[colG];
      const float w30 = S.w3s[0][colG], w31 = S.w3s[1][colG], w32 = S.w3s[2][colG];
      #pragma unroll
      for (int m = 0; m < 2; ++m)
        #pragma unroll
        for (int r = 0; r < 4; ++r) {
          const float h = fmaxf(acc[m][n][r] + b2c, 0.f);
          p[m][r][0] += h * w30; p[m][r][1] += h * w31; p[m][r][2] += h * w32;
        }
    }
  }

  // ---- reduce p over the 16 col-lanes
  #pragma unroll
  for (int m = 0; m < 2; ++m)
    #pragma unroll
    for (int r = 0; r < 4; ++r)
      #pragma unroll
      for (int jj = 0; jj < 3; ++jj) {
        float v = p[m][r][jj];
        v += __shfl_xor(v, 1); v += __shfl_xor(v, 2);
        v += __shfl_xor(v, 4); v += __shfl_xor(v, 8);
        p[m][r][jj] = v;
      }
  if (l15 == 0) {
    #pragma unroll
    for (int m = 0; m < 2; ++m)
      #pragma unroll
      for (int r = 0; r < 4; ++r) {
        const int rl = 16 * m + hi * 4 + r;   // 0..31 within wave rows
        S.red[wv][rl][0] = p[m][r][0];
        S.red[wv][rl][1] = p[m][r][1];
        S.red[wv][rl][2] = p[m][r][2];
      }
  }
  __syncthreads();

  if (t < 192) {
    const int row = t / 3, jj = t - (t / 3) * 3;
    const int wg = (row >> 5) * 4, rl = row & 31;
    float v = b3[jj] + S.red[wg][rl][jj] + S.red[wg + 1][rl][jj]
                     + S.red[wg + 2][rl][jj] + S.red[wg + 3][rl][jj];
    if (ST == 0) S.ext[row][jj] = v;
    else if (r0 + row < NROWS) out_pc[(size_t)(r0 + row) * 3 + jj] = v;
  }
  __syncthreads();
}

__global__ __launch_bounds__(512, 4) void fold3_kernel(
    const float* __restrict__ grid2, const float* __restrict__ h1b,
    const unsigned short* __restrict__ w2T,
    const float* __restrict__ f1w1, const float* __restrict__ f1b2,
    const float* __restrict__ f1w3, const float* __restrict__ f1b3,
    const float* __restrict__ f2w1, const float* __restrict__ f2b2,
    const float* __restrict__ f2w3, const float* __restrict__ f2b3,
    float* __restrict__ out_pc)
{
  __shared__ Fold3Smem S;
  const int t = threadIdx.x;
  const int r0 = blockIdx.x * 64;
  const int b0 = min(r0 / MQ, NBATCH - 1);
  const int b1 = min(b0 + 1, NBATCH - 1);

  if (t < 64) {
    const int r = r0 + t;
    const int bb = min(r / MQ, NBATCH - 1);
    S.rowb[t] = bb - b0;
    const int m = min(r - bb * MQ, MQ - 1);
    S.ext[t][0] = grid2[m * 2 + 0];
    S.ext[t][1] = grid2[m * 2 + 1];
    S.ext[t][2] = 0.f;
  }
  for (int i = t; i < 2048; i += 512) {
    const int st = i >> 10, sl = (i >> 9) & 1, c = i & 511;
    S.h1bL[st][sl][c] = h1b[st * 8192 + (sl ? b1 : b0) * 512 + c];
  }
  __syncthreads();

  fold3_stage<0>(S, t, r0, w2T,          f1w1, f1b2, f1w3, f1b3, nullptr);
  fold3_stage<1>(S, t, r0, w2T + 262144, f2w1, f2b2, f2w3, f2b3, out_pc);
}

// =====================================================================
// Chamfer A / B (unchanged from R3, passed)
// =====================================================================
__global__ __launch_bounds__(256) void chamA_kernel(const float* __restrict__ pts,
                                                    const float* __restrict__ pc,
                                                    float* __restrict__ lacc)
{
  __shared__ float sbx[2048], sby[2048], sbz[2048];
  const int t = threadIdx.x;
  const int b = blockIdx.x >> 5;
  const int n0 = (blockIdx.x & 31) << 6;
  const float* pcb = pc + (size_t)b * (MQ * 3);
  for (int i = t; i < MQ * 3; i += 256) {
    float v = pcb[i];
    int m = i / 3, j = i - m * 3;
    if (j == 0) sbx[m] = v; else if (j == 1) sby[m] = v; else sbz[m] = v;
  }
  for (int i = MQ + t; i < 2048; i += 256) { sbx[i] = 1e30f; sby[i] = 1e30f; sbz[i] = 1e30f; }
  __syncthreads();

  const int pid = t >> 4, q = t & 15;
  float ax[4], ay[4], az[4], mn[4];
  #pragma unroll
  for (int j = 0; j < 4; ++j) {
    const int n = n0 + pid * 4 + j;
    float4 P = *(const float4*)(pts + ((size_t)b * NPTS + n) * 4);
    ax[j] = P.x; ay[j] = P.y; az[j] = P.z + P.w; mn[j] = 1e30f;
  }
  #pragma unroll 4
  for (int i = 0; i < 32; ++i) {
    const int m4 = q * 4 + i * 64;
    float4 bx = *(const float4*)&sbx[m4];
    float4 by = *(const float4*)&sby[m4];
    float4 bz = *(const float4*)&sbz[m4];
    #pragma unroll
    for (int j = 0; j < 4; ++j) {
      float d0, dx, dy, dz;
      dx = ax[j] - bx.x; dy = ay[j] - by.x; dz = az[j] - bz.x; d0 = dx*dx + dy*dy + dz*dz; mn[j] = fminf(mn[j], d0);
      dx = ax[j] - bx.y; dy = ay[j] - by.y; dz = az[j] - bz.y; d0 = dx*dx + dy*dy + dz*dz; mn[j] = fminf(mn[j], d0);
      dx = ax[j] - bx.z; dy = ay[j] - by.z; dz = az[j] - bz.z; d0 = dx*dx + dy*dy + dz*dz; mn[j] = fminf(mn[j], d0);
      dx = ax[j] - bx.w; dy = ay[j] - by.w; dz = az[j] - bz.w; d0 = dx*dx + dy*dy + dz*dz; mn[j] = fminf(mn[j], d0);
    }
  }
  #pragma unroll
  for (int j = 0; j < 4; ++j) {
    mn[j] = fminf(mn[j], __shfl_xor(mn[j], 1));
    mn[j] = fminf(mn[j], __shfl_xor(mn[j], 2));
    mn[j] = fminf(mn[j], __shfl_xor(mn[j], 4));
    mn[j] = fminf(mn[j], __shfl_xor(mn[j], 8));
  }
  float v = (q == 0) ? (mn[0] + mn[1] + mn[2] + mn[3]) : 0.f;
  v += __shfl_xor(v, 16); v += __shfl_xor(v, 32);
  if ((t & 63) == 0) atomicAdd(lacc, v);
}

__global__ __launch_bounds__(256) void chamB_kernel(const float* __restrict__ pts,
                                                    const float* __restrict__ pc,
                                                    float* __restrict__ lacc)
{
  __shared__ float sax[2048], say[2048], saz[2048];
  const int t = threadIdx.x;
  const int b = blockIdx.x >> 5;
  const int m0 = (blockIdx.x & 31) << 6;
  for (int i = t; i < NPTS; i += 256) {
    float4 pp = *(const float4*)(pts + ((size_t)b * NPTS + i) * 4);
    sax[i] = pp.x; say[i] = pp.y; saz[i] = pp.z + pp.w;
  }
  __syncthreads();

  const int pid = t >> 4, q = t & 15;
  float bx[4], by[4], bz[4], mn[4];
  bool vld[4];
  #pragma unroll
  for (int j = 0; j < 4; ++j) {
    const int m = m0 + pid * 4 + j;
    vld[j] = (m < MQ);
    const int mc = vld[j] ? m : (MQ - 1);
    bx[j] = pc[(size_t)b * (MQ * 3) + mc * 3 + 0];
    by[j] = pc[(size_t)b * (MQ * 3) + mc * 3 + 1];
    bz[j] = pc[(size_t)b * (MQ * 3) + mc * 3 + 2];
    mn[j] = 1e30f;
  }
  #pragma unroll 4
  for (int i = 0; i < 32; ++i) {
    const int n4 = q * 4 + i * 64;
    float4 axv = *(const float4*)&sax[n4];
    float4 ayv = *(const float4*)&say[n4];
    float4 azv = *(const float4*)&saz[n4];
    #pragma unroll
    for (int j = 0; j < 4; ++j) {
      float d0, dx, dy, dz;
      dx = axv.x - bx[j]; dy = ayv.x - by[j]; dz = azv.x - bz[j]; d0 = dx*dx + dy*dy + dz*dz; mn[j] = fminf(mn[j], d0);
      dx = axv.y - bx[j]; dy = ayv.y - by[j]; dz = azv.y - bz[j]; d0 = dx*dx + dy*dy + dz*dz; mn[j] = fminf(mn[j], d0);
      dx = axv.z - bx[j]; dy = ayv.z - by[j]; dz = azv.z - bz[j]; d0 = dx*dx + dy*dy + dz*dz; mn[j] = fminf(mn[j], d0);
      dx = axv.w - bx[j]; dy = ayv.w - by[j]; dz = azv.w - bz[j]; d0 = dx*dx + dy*dy + dz*dz; mn[j] = fminf(mn[j], d0);
    }
  }
  #pragma unroll
  for (int j = 0; j < 4; ++j) {
    mn[j] = fminf(mn[j], __shfl_xor(mn[j], 1));
    mn[j] = fminf(mn[j], __shfl_xor(mn[j], 2));
    mn[j] = fminf(mn[j], __shfl_xor(mn[j], 4));
    mn[j] = fminf(mn[j], __shfl_xor(mn[j], 8));
  }
  float v = 0.f;
  if (q == 0) {
    #pragma unroll
    for (int j = 0; j < 4; ++j) if (vld[j]) v += mn[j];
  }
  v += __shfl_xor(v, 16); v += __shfl_xor(v, 32);
  if ((t & 63) == 0) atomicAdd(lacc + 1, v);
}

__global__ void fin_kernel(const float* __restrict__ lacc, float* __restrict__ loss) {
  if (threadIdx.x == 0 && blockIdx.x == 0)
    loss[0] = lacc[0] * (1.0f / (NBATCH * NPTS)) + lacc[1] * (1.0f / (NBATCH * MQ));
}

// =====================================================================
extern "C" void kernel_launch(void* const* d_in, const int* in_sizes, int n_in,
                              void* d_out, int out_size, void* d_ws, size_t ws_size,
                              hipStream_t stream) {
  const float* pts  = (const float*)d_in[0];
  const float* ew1  = (const float*)d_in[1];
  const float* eb1  = (const float*)d_in[2];
  const float* ew2  = (const float*)d_in[3];
  const float* eb2  = (const float*)d_in[4];
  const float* ew3  = (const float*)d_in[5];
  const float* eb3  = (const float*)d_in[6];
  const float* f1w1 = (const float*)d_in[7];
  const float* f1b1 = (const float*)d_in[8];
  const float* f1w2 = (const float*)d_in[9];
  const float* f1b2 = (const float*)d_in[10];
  const float* f1w3 = (const float*)d_in[11];
  const float* f1b3 = (const float*)d_in[12];
  const float* f2w1 = (const float*)d_in[13];
  const float* f2b1 = (const float*)d_in[14];
  const float* f2w2 = (const float*)d_in[15];
  const float* f2b2 = (const float*)d_in[16];
  const float* f2w3 = (const float*)d_in[17];
  const float* f2b3 = (const float*)d_in[18];
  const float* grid2= (const float*)d_in[19];

  float* out = (float*)d_out;
  unsigned* keys       = (unsigned*)d_ws;                              // 32768 B
  float* lacc          = (float*)((char*)d_ws + 32768);                // -> 33024
  float* h1b           = (float*)((char*)d_ws + 33024);                // 65536 B -> 98560
  unsigned short* w2T  = (unsigned short*)((char*)d_ws + 98560);       // 1 MB -> 1147136
  unsigned short* ew2T = (unsigned short*)((char*)d_ws + 1147136);     // 16 KB
  unsigned short* ew3T = (unsigned short*)((char*)d_ws + 1163520);     // 128 KB

  hipMemsetAsync(d_ws, 0, 98560, stream);   // keys + lacc + h1b

  tconv_kernel<<<584, 256, 0, stream>>>(f1w2, f2w2, ew2, ew3, w2T, ew2T, ew3T);
  enc2_kernel<<<512, 512, 0, stream>>>(pts, ew1, eb1, ew2T, eb2, ew3T, eb3, keys);
  decode_kernel<<<32, 256, 0, stream>>>(keys, out);                    // theta
  h1base_kernel<<<128, 256, 0, stream>>>(out, f1w1, f1b1, f2w1, f2b1, h1b);
  fold3_kernel<<<507, 512, 0, stream>>>(grid2, h1b, w2T,
                                        f1w1, f1b2, f1w3, f1b3,
                                        f2w1, f2b2, f2w3, f2b3,
                                        out + 8192);                   // pc_out
  chamA_kernel<<<512, 256, 0, stream>>>(pts, out + 8192, lacc);
  chamB_kernel<<<512, 256, 0, stream>>>(pts, out + 8192, lacc);
  fin_kernel<<<1, 64, 0, stream>>>(lacc, out + 8192 + 97200);          // loss
}